// Round 2
// baseline (756.990 us; speedup 1.0000x reference)
//
#include <hip/hip_runtime.h>

#define BB 8
#define TIN 168
#define NN 1500
#define TOUTC 24
#define TLEN 162
#define NG 32
#define NTH 768
#define SN 2
#define TOPKK 12

// workspace offsets (in 4-byte elements)
#define OFF_M1   0
#define OFF_M2   24000
#define OFF_EW   48000
#define OFF_EB   48112
#define OFF_ADJW 48128
#define OFF_ADJI 67628
#define OFF_PART 87136
// total ws need: (87136 + 8*32*24*1500)*4 = 46,428,544 bytes

__device__ __forceinline__ unsigned short f2bf(float f) {
    unsigned int u = __float_as_uint(f);
    unsigned int r = (u + 0x7fffu + ((u >> 16) & 1u)) >> 16;
    return (unsigned short)r;
}
__device__ __forceinline__ float bf2f(unsigned short s) {
    return __uint_as_float(((unsigned int)s) << 16);
}

// ---------------- prep: m1/m2 embeddings + effective inception taps ----------------
__global__ __launch_bounds__(256) void prep_kernel(
    const float* __restrict__ e1, const float* __restrict__ e2,
    const float* __restrict__ gw1, const float* __restrict__ gb1,
    const float* __restrict__ gw2, const float* __restrict__ gb2,
    const float* __restrict__ pw, const float* __restrict__ pb,
    const float* __restrict__ tw2, const float* __restrict__ tb2,
    const float* __restrict__ tw3, const float* __restrict__ tb3,
    const float* __restrict__ tw6, const float* __restrict__ tb6,
    const float* __restrict__ tw7, const float* __restrict__ tb7,
    float* __restrict__ ws)
{
    int n = blockIdx.x * blockDim.x + threadIdx.x;
    if (n < NN) {
        float a1[16], a2[16];
        #pragma unroll
        for (int o = 0; o < 16; ++o) { a1[o] = gb1[o]; a2[o] = gb2[o]; }
        #pragma unroll
        for (int i = 0; i < 16; ++i) {
            float u = e1[n*16+i], v = e2[n*16+i];
            #pragma unroll
            for (int o = 0; o < 16; ++o) {
                a1[o] += u * gw1[i*16+o];
                a2[o] += v * gw2[i*16+o];
            }
        }
        #pragma unroll
        for (int o = 0; o < 16; ++o) {
            ws[OFF_M1 + n*16+o] = tanhf(1.5f*a1[o]);
            ws[OFF_M2 + n*16+o] = tanhf(1.5f*a2[o]);
        }
    }
    if (blockIdx.x == 0 && threadIdx.x < 16) {
        int c = threadIdx.x;
        int br = c >> 2, oc = c & 3;
        const float* tw; const float* tb; int k;
        if (br == 0)      { tw = tw2; tb = tb2; k = 2; }
        else if (br == 1) { tw = tw3; tb = tb3; k = 3; }
        else if (br == 2) { tw = tw6; tb = tb6; k = 6; }
        else              { tw = tw7; tb = tb7; k = 7; }
        for (int d = 0; d < 7; ++d) ws[OFF_EW + c*7 + d] = 0.f;
        float ebv = tb[oc];
        for (int j = 0; j < k; ++j) {
            float s = 0.f, sb = 0.f;
            for (int ic = 0; ic < 16; ++ic) {
                float w = tw[(oc*16+ic)*k + j];
                s  += w * pw[ic];
                sb += w * pb[ic];
            }
            ws[OFF_EW + c*7 + (7-k+j)] = s;
            ebv += sb;
        }
        ws[OFF_EB + c] = ebv;
    }
}

// ---------------- graph: scores + top-12 + row-normalized sparse adjacency ----------------
__global__ __launch_bounds__(256) void graph_kernel(float* __restrict__ ws)
{
    const float* m1 = ws + OFF_M1;
    const float* m2 = ws + OFF_M2;
    float* adjw = ws + OFF_ADJW;
    int*   adji = (int*)ws + OFF_ADJI;
    int v = blockIdx.x;
    int tid = threadIdx.x;
    __shared__ float sc[NN];
    __shared__ float rv[256];
    __shared__ int   ri[256];
    __shared__ float m1v[16], m2v[16];
    if (tid < 16) { m1v[tid] = m1[v*16+tid]; m2v[tid] = m2[v*16+tid]; }
    __syncthreads();
    for (int j = tid; j < NN; j += 256) {
        float d = 0.f;
        #pragma unroll
        for (int i = 0; i < 16; ++i) d += m1v[i]*m2[j*16+i] - m2v[i]*m1[j*16+i];
        float a = tanhf(1.5f*d);
        sc[j] = a > 0.f ? a : 0.f;
    }
    __syncthreads();
    for (int it = 0; it < TOPKK; ++it) {
        float bv = -1.f; int bi = NN;
        for (int j = tid; j < NN; j += 256) {   // ascending scan + strict '>' keeps lowest index on ties
            float q = sc[j];
            if (q > bv) { bv = q; bi = j; }
        }
        rv[tid] = bv; ri[tid] = bi;
        __syncthreads();
        for (int s = 128; s > 0; s >>= 1) {
            if (tid < s) {
                float ov = rv[tid+s]; int oi = ri[tid+s];
                if (ov > rv[tid] || (ov == rv[tid] && oi < ri[tid])) { rv[tid] = ov; ri[tid] = oi; }
            }
            __syncthreads();
        }
        if (tid == 0) {
            adjw[v*13+it] = rv[0];
            adji[v*13+it] = ri[0];
            sc[ri[0]] = -1.f;
        }
        __syncthreads();
    }
    if (tid == 0) {
        float s = 1.f;
        #pragma unroll
        for (int it = 0; it < TOPKK; ++it) s += adjw[v*13+it];
        float inv = 1.f/s;
        #pragma unroll
        for (int it = 0; it < TOPKK; ++it) adjw[v*13+it] *= inv;
        adji[v*13+12] = v;
        adjw[v*13+12] = inv;   // normalized self-loop
    }
}

// ---------------- main: h1 -> hop1 -> hop2 -> MLP, per (b, t-group) block ----------------
// Spill-free restructure: only yacc[SN][24] + h1v[SN][16] persist across phases.
// Full MLP lives in phase D, reading own-node hop1 back from LDS (bf16).
__global__ __launch_bounds__(NTH, 3) void main_kernel(
    const float* __restrict__ x, float* __restrict__ ws,
    const float* __restrict__ mw, const float* __restrict__ mb,
    const float* __restrict__ rw1, const float* __restrict__ rb1,
    const float* __restrict__ rw2, const float* __restrict__ rb2)
{
    const float* ew   = ws + OFF_EW;
    const float* eb   = ws + OFF_EB;
    const float* adjw = ws + OFF_ADJW;
    const int*   adji = (const int*)ws + OFF_ADJI;
    float*       part = ws + OFF_PART;

    // rotated-chunk layouts: chunk k (channels 4k..4k+3) of node n lives at slot n*4 + ((k+n)&3)
    __shared__ float4  sl4[NN*4];   // 96000 B : h1 slice fp32
    __shared__ ushort4 hb4[NN*4];   // 48000 B : hop1 slice bf16

    const int tid = threadIdx.x;
    const int b = blockIdx.x >> 5;
    const int g = blockIdx.x & 31;
    const int t0 = (g*TLEN) >> 5;
    const int t1 = ((g+1)*TLEN) >> 5;

    float yacc[SN][TOUTC];
    #pragma unroll
    for (int s = 0; s < SN; ++s)
        #pragma unroll
        for (int o = 0; o < TOUTC; ++o) yacc[s][o] = 0.f;

    for (int t = t0; t < t1; ++t) {
        float h1v[SN][16];
        // ---- Phase A: effective 7-tap conv -> h1 slice into LDS (and regs) ----
        #pragma unroll
        for (int s = 0; s < SN; ++s) {
            int v = tid + NTH*s;
            if (v < NN) {
                float xv[7];
                #pragma unroll
                for (int d = 0; d < 7; ++d) xv[d] = x[(b*TIN + t + d)*NN + v];
                #pragma unroll
                for (int k = 0; k < 4; ++k) {
                    float hc[4];
                    #pragma unroll
                    for (int u = 0; u < 4; ++u) {
                        int c = 4*k + u;
                        float a = eb[c];
                        #pragma unroll
                        for (int d = 0; d < 7; ++d) a += ew[c*7+d]*xv[d];
                        a = a > 0.f ? a : 0.f;
                        hc[u] = a;
                        h1v[s][c] = a;
                    }
                    sl4[v*4 + ((k+v)&3)] = make_float4(hc[0],hc[1],hc[2],hc[3]);
                }
            }
        }
        __syncthreads();
        // ---- Phase B: hop1 = 0.2*h1 + 0.8*A@h1 ; store bf16 only ----
        #pragma unroll
        for (int s = 0; s < SN; ++s) {
            int v = tid + NTH*s;
            if (v < NN) {
                float hop1[16];
                #pragma unroll
                for (int c = 0; c < 16; ++c) hop1[c] = 0.2f*h1v[s][c];
                int base = v*13;
                #pragma unroll
                for (int j = 0; j < 13; ++j) {
                    int nb = adji[base+j];
                    float wj = 0.8f*adjw[base+j];
                    #pragma unroll
                    for (int k = 0; k < 4; ++k) {
                        float4 gv = sl4[nb*4 + ((k+nb)&3)];
                        hop1[4*k+0] += wj*gv.x;
                        hop1[4*k+1] += wj*gv.y;
                        hop1[4*k+2] += wj*gv.z;
                        hop1[4*k+3] += wj*gv.w;
                    }
                }
                #pragma unroll
                for (int k = 0; k < 4; ++k) {
                    ushort4 u4;
                    u4.x = f2bf(hop1[4*k+0]);
                    u4.y = f2bf(hop1[4*k+1]);
                    u4.z = f2bf(hop1[4*k+2]);
                    u4.w = f2bf(hop1[4*k+3]);
                    hb4[v*4 + ((k+v)&3)] = u4;
                }
            }
        }
        __syncthreads();
        // ---- Phase D: hop2 gather + full 48->16->16->24 MLP ; accumulate mean ----
        #pragma unroll
        for (int s = 0; s < SN; ++s) {
            int v = tid + NTH*s;
            if (v < NN) {
                float hop1o[16];
                #pragma unroll
                for (int k = 0; k < 4; ++k) {
                    ushort4 u4 = hb4[v*4 + ((k+v)&3)];
                    hop1o[4*k+0] = bf2f(u4.x);
                    hop1o[4*k+1] = bf2f(u4.y);
                    hop1o[4*k+2] = bf2f(u4.z);
                    hop1o[4*k+3] = bf2f(u4.w);
                }
                float hop2[16];
                #pragma unroll
                for (int c = 0; c < 16; ++c) hop2[c] = 0.2f*h1v[s][c];
                int base = v*13;
                #pragma unroll
                for (int j = 0; j < 13; ++j) {
                    int nb = adji[base+j];
                    float wj = 0.8f*adjw[base+j];
                    #pragma unroll
                    for (int k = 0; k < 4; ++k) {
                        ushort4 u4 = hb4[nb*4 + ((k+nb)&3)];
                        hop2[4*k+0] += wj*bf2f(u4.x);
                        hop2[4*k+1] += wj*bf2f(u4.y);
                        hop2[4*k+2] += wj*bf2f(u4.z);
                        hop2[4*k+3] += wj*bf2f(u4.w);
                    }
                }
                float yr[16];
                #pragma unroll
                for (int o = 0; o < 16; ++o) {
                    float a = mb[o];
                    #pragma unroll
                    for (int c = 0; c < 16; ++c) a += mw[o*48+c]    * h1v[s][c];
                    #pragma unroll
                    for (int c = 0; c < 16; ++c) a += mw[o*48+16+c] * hop1o[c];
                    #pragma unroll
                    for (int c = 0; c < 16; ++c) a += mw[o*48+32+c] * hop2[c];
                    yr[o] = a > 0.f ? a : 0.f;
                }
                float r16[16];
                #pragma unroll
                for (int o = 0; o < 16; ++o) {
                    float a = rb1[o];
                    #pragma unroll
                    for (int i = 0; i < 16; ++i) a += rw1[o*16+i]*yr[i];
                    r16[o] = a > 0.f ? a : 0.f;
                }
                #pragma unroll
                for (int o = 0; o < TOUTC; ++o) {
                    float a = rb2[o];
                    #pragma unroll
                    for (int i = 0; i < 16; ++i) a += rw2[o*16+i]*r16[i];
                    yacc[s][o] += a;
                }
            }
        }
        // Phase D no longer touches sl4, so next A's sl4 writes are safe;
        // next B's hb4 writes are ordered by the post-A barrier.
    }
    #pragma unroll
    for (int s = 0; s < SN; ++s) {
        int v = tid + NTH*s;
        if (v < NN) {
            #pragma unroll
            for (int o = 0; o < TOUTC; ++o)
                part[((b*NG + g)*TOUTC + o)*NN + v] = yacc[s][o];
        }
    }
}

// ---------------- reduce: sum 32 t-group partials, scale by 1/162 ----------------
__global__ __launch_bounds__(256) void reduce_kernel(const float* __restrict__ ws, float* __restrict__ out)
{
    const float* part = ws + OFF_PART;
    int idx = blockIdx.x*256 + threadIdx.x;
    if (idx >= BB*TOUTC*NN) return;
    int v = idx % NN;
    int rest = idx / NN;
    int o = rest % TOUTC;
    int b = rest / TOUTC;
    float s = 0.f;
    #pragma unroll
    for (int g = 0; g < NG; ++g)
        s += part[((b*NG + g)*TOUTC + o)*NN + v];
    out[idx] = s * (1.0f/TLEN);
}

extern "C" void kernel_launch(void* const* d_in, const int* in_sizes, int n_in,
                              void* d_out, int out_size, void* d_ws, size_t ws_size,
                              hipStream_t stream)
{
    const float* x   = (const float*)d_in[0];
    const float* pw  = (const float*)d_in[1];
    const float* pb  = (const float*)d_in[2];
    const float* tw2 = (const float*)d_in[3];
    const float* tb2 = (const float*)d_in[4];
    const float* tw3 = (const float*)d_in[5];
    const float* tb3 = (const float*)d_in[6];
    const float* tw6 = (const float*)d_in[7];
    const float* tb6 = (const float*)d_in[8];
    const float* tw7 = (const float*)d_in[9];
    const float* tb7 = (const float*)d_in[10];
    const float* e1  = (const float*)d_in[11];
    const float* e2  = (const float*)d_in[12];
    const float* gw1 = (const float*)d_in[13];
    const float* gb1 = (const float*)d_in[14];
    const float* gw2 = (const float*)d_in[15];
    const float* gb2 = (const float*)d_in[16];
    const float* mw  = (const float*)d_in[17];
    const float* mb  = (const float*)d_in[18];
    const float* rw1 = (const float*)d_in[19];
    const float* rb1 = (const float*)d_in[20];
    const float* rw2 = (const float*)d_in[21];
    const float* rb2 = (const float*)d_in[22];
    float* ws  = (float*)d_ws;
    float* out = (float*)d_out;

    prep_kernel<<<(NN + 255)/256, 256, 0, stream>>>(e1,e2,gw1,gb1,gw2,gb2,pw,pb,
                                                    tw2,tb2,tw3,tb3,tw6,tb6,tw7,tb7, ws);
    graph_kernel<<<NN, 256, 0, stream>>>(ws);
    main_kernel<<<BB*NG, NTH, 0, stream>>>(x, ws, mw, mb, rw1, rb1, rw2, rb2);
    reduce_kernel<<<(BB*TOUTC*NN + 255)/256, 256, 0, stream>>>(ws, out);
}

// Round 3
// 578.467 us; speedup vs baseline: 1.3086x; 1.3086x over previous
//
#include <hip/hip_runtime.h>

#define BB 8
#define TIN 168
#define NN 1500
#define TOUTC 24
#define TLEN 162
#define NG 32
#define NTH 768
#define SN 2
#define TOPKK 12

// workspace offsets (in 4-byte elements)
#define OFF_M1   0
#define OFF_M2   24000
#define OFF_EW   48000
#define OFF_EB   48112
#define OFF_ADJW 48128
#define OFF_ADJI 67628
#define OFF_PART 87136
// part is now [b][g][c=16][v] : 8*32*16*1500 floats = 24.58 MB
// total ws need: (87136 + 6144000)*4 = 24,924,544 bytes

__device__ __forceinline__ unsigned short f2bf(float f) {
    unsigned int u = __float_as_uint(f);
    unsigned int r = (u + 0x7fffu + ((u >> 16) & 1u)) >> 16;
    return (unsigned short)r;
}
__device__ __forceinline__ float bf2f(unsigned short s) {
    return __uint_as_float(((unsigned int)s) << 16);
}

// ---------------- prep: m1/m2 embeddings + effective inception taps ----------------
__global__ __launch_bounds__(256) void prep_kernel(
    const float* __restrict__ e1, const float* __restrict__ e2,
    const float* __restrict__ gw1, const float* __restrict__ gb1,
    const float* __restrict__ gw2, const float* __restrict__ gb2,
    const float* __restrict__ pw, const float* __restrict__ pb,
    const float* __restrict__ tw2, const float* __restrict__ tb2,
    const float* __restrict__ tw3, const float* __restrict__ tb3,
    const float* __restrict__ tw6, const float* __restrict__ tb6,
    const float* __restrict__ tw7, const float* __restrict__ tb7,
    float* __restrict__ ws)
{
    int n = blockIdx.x * blockDim.x + threadIdx.x;
    if (n < NN) {
        float a1[16], a2[16];
        #pragma unroll
        for (int o = 0; o < 16; ++o) { a1[o] = gb1[o]; a2[o] = gb2[o]; }
        #pragma unroll
        for (int i = 0; i < 16; ++i) {
            float u = e1[n*16+i], v = e2[n*16+i];
            #pragma unroll
            for (int o = 0; o < 16; ++o) {
                a1[o] += u * gw1[i*16+o];
                a2[o] += v * gw2[i*16+o];
            }
        }
        #pragma unroll
        for (int o = 0; o < 16; ++o) {
            ws[OFF_M1 + n*16+o] = tanhf(1.5f*a1[o]);
            ws[OFF_M2 + n*16+o] = tanhf(1.5f*a2[o]);
        }
    }
    if (blockIdx.x == 0 && threadIdx.x < 16) {
        int c = threadIdx.x;
        int br = c >> 2, oc = c & 3;
        const float* tw; const float* tb; int k;
        if (br == 0)      { tw = tw2; tb = tb2; k = 2; }
        else if (br == 1) { tw = tw3; tb = tb3; k = 3; }
        else if (br == 2) { tw = tw6; tb = tb6; k = 6; }
        else              { tw = tw7; tb = tb7; k = 7; }
        for (int d = 0; d < 7; ++d) ws[OFF_EW + c*7 + d] = 0.f;
        float ebv = tb[oc];
        for (int j = 0; j < k; ++j) {
            float s = 0.f, sb = 0.f;
            for (int ic = 0; ic < 16; ++ic) {
                float w = tw[(oc*16+ic)*k + j];
                s  += w * pw[ic];
                sb += w * pb[ic];
            }
            ws[OFF_EW + c*7 + (7-k+j)] = s;
            ebv += sb;
        }
        ws[OFF_EB + c] = ebv;
    }
}

// ---------------- graph: scores + top-12 + row-normalized sparse adjacency ----------------
__global__ __launch_bounds__(256) void graph_kernel(float* __restrict__ ws)
{
    const float* m1 = ws + OFF_M1;
    const float* m2 = ws + OFF_M2;
    float* adjw = ws + OFF_ADJW;
    int*   adji = (int*)ws + OFF_ADJI;
    int v = blockIdx.x;
    int tid = threadIdx.x;
    __shared__ float sc[NN];
    __shared__ float rv[256];
    __shared__ int   ri[256];
    __shared__ float m1v[16], m2v[16];
    if (tid < 16) { m1v[tid] = m1[v*16+tid]; m2v[tid] = m2[v*16+tid]; }
    __syncthreads();
    for (int j = tid; j < NN; j += 256) {
        float d = 0.f;
        #pragma unroll
        for (int i = 0; i < 16; ++i) d += m1v[i]*m2[j*16+i] - m2v[i]*m1[j*16+i];
        float a = tanhf(1.5f*d);
        sc[j] = a > 0.f ? a : 0.f;
    }
    __syncthreads();
    for (int it = 0; it < TOPKK; ++it) {
        float bv = -1.f; int bi = NN;
        for (int j = tid; j < NN; j += 256) {   // ascending scan + strict '>' keeps lowest index on ties
            float q = sc[j];
            if (q > bv) { bv = q; bi = j; }
        }
        rv[tid] = bv; ri[tid] = bi;
        __syncthreads();
        for (int s = 128; s > 0; s >>= 1) {
            if (tid < s) {
                float ov = rv[tid+s]; int oi = ri[tid+s];
                if (ov > rv[tid] || (ov == rv[tid] && oi < ri[tid])) { rv[tid] = ov; ri[tid] = oi; }
            }
            __syncthreads();
        }
        if (tid == 0) {
            adjw[v*13+it] = rv[0];
            adji[v*13+it] = ri[0];
            sc[ri[0]] = -1.f;
        }
        __syncthreads();
    }
    if (tid == 0) {
        float s = 1.f;
        #pragma unroll
        for (int it = 0; it < TOPKK; ++it) s += adjw[v*13+it];
        float inv = 1.f/s;
        #pragma unroll
        for (int it = 0; it < TOPKK; ++it) adjw[v*13+it] *= inv;
        adji[v*13+12] = v;
        adjw[v*13+12] = inv;   // normalized self-loop
    }
}

// ---------------- main: h1 -> hop1 -> hop2 -> MLP(r16), per (b, t-group) block ----------------
// Register-pressure-first design: the ONLY state persisting across phases is
// racc[SN][16] (post-relu r16 accumulator; rw2/rb2/mean applied in reduce_kernel
// by linearity). Everything else round-trips through LDS. Peak live ~80 VGPRs.
__global__ __launch_bounds__(NTH, 3) void main_kernel(
    const float* __restrict__ x, float* __restrict__ ws,
    const float* __restrict__ mw, const float* __restrict__ mb,
    const float* __restrict__ rw1, const float* __restrict__ rb1)
{
    const float* ew   = ws + OFF_EW;
    const float* eb   = ws + OFF_EB;
    const float* adjw = ws + OFF_ADJW;
    const int*   adji = (const int*)ws + OFF_ADJI;
    float*       part = ws + OFF_PART;

    // rotated-chunk layouts: chunk k (channels 4k..4k+3) of node n lives at slot n*4 + ((k+n)&3)
    __shared__ float4  sl4[NN*4];   // 96000 B : h1 slice fp32
    __shared__ ushort4 hb4[NN*4];   // 48000 B : hop1 slice bf16

    const int tid = threadIdx.x;
    const int b = blockIdx.x >> 5;
    const int g = blockIdx.x & 31;
    const int t0 = (g*TLEN) >> 5;
    const int t1 = ((g+1)*TLEN) >> 5;

    float racc[SN][16];
    #pragma unroll
    for (int s = 0; s < SN; ++s)
        #pragma unroll
        for (int o = 0; o < 16; ++o) racc[s][o] = 0.f;

    for (int t = t0; t < t1; ++t) {
        // ---- Phase A: effective 7-tap conv -> h1 slice into LDS ----
        #pragma unroll
        for (int s = 0; s < SN; ++s) {
            int v = tid + NTH*s;
            if (v < NN) {
                float xv[7];
                #pragma unroll
                for (int d = 0; d < 7; ++d) xv[d] = x[(b*TIN + t + d)*NN + v];
                #pragma unroll
                for (int k = 0; k < 4; ++k) {
                    float hc[4];
                    #pragma unroll
                    for (int u = 0; u < 4; ++u) {
                        int c = 4*k + u;
                        float a = eb[c];
                        #pragma unroll
                        for (int d = 0; d < 7; ++d) a += ew[c*7+d]*xv[d];
                        hc[u] = a > 0.f ? a : 0.f;
                    }
                    sl4[v*4 + ((k+v)&3)] = make_float4(hc[0],hc[1],hc[2],hc[3]);
                }
            }
        }
        __syncthreads();
        // ---- Phase B: hop1 = 0.2*h1own + 0.8*A@h1 ; store bf16 ----
        #pragma unroll
        for (int s = 0; s < SN; ++s) {
            int v = tid + NTH*s;
            if (v < NN) {
                float hop1[16];
                #pragma unroll
                for (int k = 0; k < 4; ++k) {
                    float4 gv = sl4[v*4 + ((k+v)&3)];
                    hop1[4*k+0] = 0.2f*gv.x;
                    hop1[4*k+1] = 0.2f*gv.y;
                    hop1[4*k+2] = 0.2f*gv.z;
                    hop1[4*k+3] = 0.2f*gv.w;
                }
                int base = v*13;
                #pragma unroll
                for (int j = 0; j < 13; ++j) {
                    int nb = adji[base+j];
                    float wj = 0.8f*adjw[base+j];
                    #pragma unroll
                    for (int k = 0; k < 4; ++k) {
                        float4 gv = sl4[nb*4 + ((k+nb)&3)];
                        hop1[4*k+0] += wj*gv.x;
                        hop1[4*k+1] += wj*gv.y;
                        hop1[4*k+2] += wj*gv.z;
                        hop1[4*k+3] += wj*gv.w;
                    }
                }
                #pragma unroll
                for (int k = 0; k < 4; ++k) {
                    ushort4 u4;
                    u4.x = f2bf(hop1[4*k+0]);
                    u4.y = f2bf(hop1[4*k+1]);
                    u4.z = f2bf(hop1[4*k+2]);
                    u4.w = f2bf(hop1[4*k+3]);
                    hb4[v*4 + ((k+v)&3)] = u4;
                }
            }
        }
        __syncthreads();
        // ---- Phase D: hop2 gather + chunk-wise mw fold + rw1 ; accumulate racc ----
        #pragma unroll
        for (int s = 0; s < SN; ++s) {
            int v = tid + NTH*s;
            if (v < NN) {
                float y16[16];
                #pragma unroll
                for (int o = 0; o < 16; ++o) y16[o] = mb[o];
                float hop2[16];
                // own h1 (fp32): hop2 base + fold mw[:,0:16]; h1own never persists
                #pragma unroll
                for (int k = 0; k < 4; ++k) {
                    float4 gv = sl4[v*4 + ((k+v)&3)];
                    float hv[4] = {gv.x, gv.y, gv.z, gv.w};
                    #pragma unroll
                    for (int u = 0; u < 4; ++u) {
                        hop2[4*k+u] = 0.2f*hv[u];
                        #pragma unroll
                        for (int o = 0; o < 16; ++o) y16[o] += mw[o*48 + 4*k+u]*hv[u];
                    }
                }
                // own hop1 (bf16): fold mw[:,16:32]
                #pragma unroll
                for (int k = 0; k < 4; ++k) {
                    ushort4 u4 = hb4[v*4 + ((k+v)&3)];
                    float hv[4] = {bf2f(u4.x), bf2f(u4.y), bf2f(u4.z), bf2f(u4.w)};
                    #pragma unroll
                    for (int u = 0; u < 4; ++u)
                        #pragma unroll
                        for (int o = 0; o < 16; ++o) y16[o] += mw[o*48+16 + 4*k+u]*hv[u];
                }
                // gather hop2
                int base = v*13;
                #pragma unroll
                for (int j = 0; j < 13; ++j) {
                    int nb = adji[base+j];
                    float wj = 0.8f*adjw[base+j];
                    #pragma unroll
                    for (int k = 0; k < 4; ++k) {
                        ushort4 u4 = hb4[nb*4 + ((k+nb)&3)];
                        hop2[4*k+0] += wj*bf2f(u4.x);
                        hop2[4*k+1] += wj*bf2f(u4.y);
                        hop2[4*k+2] += wj*bf2f(u4.z);
                        hop2[4*k+3] += wj*bf2f(u4.w);
                    }
                }
                // fold mw[:,32:48] + relu
                #pragma unroll
                for (int o = 0; o < 16; ++o) {
                    float a = y16[o];
                    #pragma unroll
                    for (int c = 0; c < 16; ++c) a += mw[o*48+32+c]*hop2[c];
                    y16[o] = a > 0.f ? a : 0.f;
                }
                // r16 = relu(rw1@yr + rb1) ; racc += r16
                #pragma unroll
                for (int o = 0; o < 16; ++o) {
                    float a = rb1[o];
                    #pragma unroll
                    for (int i = 0; i < 16; ++i) a += rw1[o*16+i]*y16[i];
                    racc[s][o] += (a > 0.f ? a : 0.f);
                }
            }
        }
        __syncthreads();   // D reads sl4/hb4; next-t A/B overwrite them
    }
    #pragma unroll
    for (int s = 0; s < SN; ++s) {
        int v = tid + NTH*s;
        if (v < NN) {
            #pragma unroll
            for (int o = 0; o < 16; ++o)
                part[((b*NG + g)*16 + o)*NN + v] = racc[s][o];
        }
    }
}

// ---------------- reduce: sum 32 t-group racc partials, apply rw2/rb2, mean ----------------
__global__ __launch_bounds__(256) void reduce_kernel(const float* __restrict__ ws,
                                                     const float* __restrict__ rw2,
                                                     const float* __restrict__ rb2,
                                                     float* __restrict__ out)
{
    const float* part = ws + OFF_PART;
    int idx = blockIdx.x*256 + threadIdx.x;   // idx over b*NN + v
    if (idx >= BB*NN) return;
    int v = idx % NN;
    int b = idx / NN;
    float s16[16];
    #pragma unroll
    for (int c = 0; c < 16; ++c) s16[c] = 0.f;
    for (int g = 0; g < NG; ++g) {
        #pragma unroll
        for (int c = 0; c < 16; ++c)
            s16[c] += part[((b*NG + g)*16 + c)*NN + v];
    }
    #pragma unroll
    for (int c = 0; c < 16; ++c) s16[c] *= (1.0f/TLEN);
    #pragma unroll
    for (int o = 0; o < TOUTC; ++o) {
        float a = rb2[o];
        #pragma unroll
        for (int c = 0; c < 16; ++c) a += rw2[o*16+c]*s16[c];
        out[(b*TOUTC + o)*NN + v] = a;
    }
}

extern "C" void kernel_launch(void* const* d_in, const int* in_sizes, int n_in,
                              void* d_out, int out_size, void* d_ws, size_t ws_size,
                              hipStream_t stream)
{
    const float* x   = (const float*)d_in[0];
    const float* pw  = (const float*)d_in[1];
    const float* pb  = (const float*)d_in[2];
    const float* tw2 = (const float*)d_in[3];
    const float* tb2 = (const float*)d_in[4];
    const float* tw3 = (const float*)d_in[5];
    const float* tb3 = (const float*)d_in[6];
    const float* tw6 = (const float*)d_in[7];
    const float* tb6 = (const float*)d_in[8];
    const float* tw7 = (const float*)d_in[9];
    const float* tb7 = (const float*)d_in[10];
    const float* e1  = (const float*)d_in[11];
    const float* e2  = (const float*)d_in[12];
    const float* gw1 = (const float*)d_in[13];
    const float* gb1 = (const float*)d_in[14];
    const float* gw2 = (const float*)d_in[15];
    const float* gb2 = (const float*)d_in[16];
    const float* mw  = (const float*)d_in[17];
    const float* mb  = (const float*)d_in[18];
    const float* rw1 = (const float*)d_in[19];
    const float* rb1 = (const float*)d_in[20];
    const float* rw2 = (const float*)d_in[21];
    const float* rb2 = (const float*)d_in[22];
    float* ws  = (float*)d_ws;
    float* out = (float*)d_out;

    prep_kernel<<<(NN + 255)/256, 256, 0, stream>>>(e1,e2,gw1,gb1,gw2,gb2,pw,pb,
                                                    tw2,tb2,tw3,tb3,tw6,tb6,tw7,tb7, ws);
    graph_kernel<<<NN, 256, 0, stream>>>(ws);
    main_kernel<<<BB*NG, NTH, 0, stream>>>(x, ws, mw, mb, rw1, rb1);
    reduce_kernel<<<(BB*NN + 255)/256, 256, 0, stream>>>(ws, rw2, rb2, out);
}

// Round 4
// 575.456 us; speedup vs baseline: 1.3155x; 1.0052x over previous
//
#include <hip/hip_runtime.h>

#define BB 8
#define TIN 168
#define NN 1500
#define TOUTC 24
#define TLEN 162
#define NG 32
#define NTH 768
#define SN 2
#define TOPKK 12

// workspace offsets (in 4-byte elements)
#define OFF_M1   0
#define OFF_M2   24000
#define OFF_EW   48000
#define OFF_EB   48112
#define OFF_ADJW 48128
#define OFF_ADJI 67628
#define OFF_PART 87136
// part is [b][g][c=16][v] : 8*32*16*1500 floats = 24.58 MB
// total ws need: (87136 + 6144000)*4 = 24,924,544 bytes

__device__ __forceinline__ unsigned short f2bf(float f) {
    unsigned int u = __float_as_uint(f);
    unsigned int r = (u + 0x7fffu + ((u >> 16) & 1u)) >> 16;
    return (unsigned short)r;
}
__device__ __forceinline__ float bf2f(unsigned short s) {
    return __uint_as_float(((unsigned int)s) << 16);
}

// ---------------- prep: m1/m2 embeddings + effective inception taps ----------------
__global__ __launch_bounds__(256) void prep_kernel(
    const float* __restrict__ e1, const float* __restrict__ e2,
    const float* __restrict__ gw1, const float* __restrict__ gb1,
    const float* __restrict__ gw2, const float* __restrict__ gb2,
    const float* __restrict__ pw, const float* __restrict__ pb,
    const float* __restrict__ tw2, const float* __restrict__ tb2,
    const float* __restrict__ tw3, const float* __restrict__ tb3,
    const float* __restrict__ tw6, const float* __restrict__ tb6,
    const float* __restrict__ tw7, const float* __restrict__ tb7,
    float* __restrict__ ws)
{
    int n = blockIdx.x * blockDim.x + threadIdx.x;
    if (n < NN) {
        float a1[16], a2[16];
        #pragma unroll
        for (int o = 0; o < 16; ++o) { a1[o] = gb1[o]; a2[o] = gb2[o]; }
        #pragma unroll
        for (int i = 0; i < 16; ++i) {
            float u = e1[n*16+i], v = e2[n*16+i];
            #pragma unroll
            for (int o = 0; o < 16; ++o) {
                a1[o] += u * gw1[i*16+o];
                a2[o] += v * gw2[i*16+o];
            }
        }
        #pragma unroll
        for (int o = 0; o < 16; ++o) {
            ws[OFF_M1 + n*16+o] = tanhf(1.5f*a1[o]);
            ws[OFF_M2 + n*16+o] = tanhf(1.5f*a2[o]);
        }
    }
    if (blockIdx.x == 0 && threadIdx.x < 16) {
        int c = threadIdx.x;
        int br = c >> 2, oc = c & 3;
        const float* tw; const float* tb; int k;
        if (br == 0)      { tw = tw2; tb = tb2; k = 2; }
        else if (br == 1) { tw = tw3; tb = tb3; k = 3; }
        else if (br == 2) { tw = tw6; tb = tb6; k = 6; }
        else              { tw = tw7; tb = tb7; k = 7; }
        for (int d = 0; d < 7; ++d) ws[OFF_EW + c*7 + d] = 0.f;
        float ebv = tb[oc];
        for (int j = 0; j < k; ++j) {
            float s = 0.f, sb = 0.f;
            for (int ic = 0; ic < 16; ++ic) {
                float w = tw[(oc*16+ic)*k + j];
                s  += w * pw[ic];
                sb += w * pb[ic];
            }
            ws[OFF_EW + c*7 + (7-k+j)] = s;
            ebv += sb;
        }
        ws[OFF_EB + c] = ebv;
    }
}

// ---------------- graph: scores + top-12 + row-normalized sparse adjacency ----------------
__global__ __launch_bounds__(256) void graph_kernel(float* __restrict__ ws)
{
    const float* m1 = ws + OFF_M1;
    const float* m2 = ws + OFF_M2;
    float* adjw = ws + OFF_ADJW;
    int*   adji = (int*)ws + OFF_ADJI;
    int v = blockIdx.x;
    int tid = threadIdx.x;
    __shared__ float sc[NN];
    __shared__ float rv[256];
    __shared__ int   ri[256];
    __shared__ float m1v[16], m2v[16];
    if (tid < 16) { m1v[tid] = m1[v*16+tid]; m2v[tid] = m2[v*16+tid]; }
    __syncthreads();
    for (int j = tid; j < NN; j += 256) {
        float d = 0.f;
        #pragma unroll
        for (int i = 0; i < 16; ++i) d += m1v[i]*m2[j*16+i] - m2v[i]*m1[j*16+i];
        float a = tanhf(1.5f*d);
        sc[j] = a > 0.f ? a : 0.f;
    }
    __syncthreads();
    for (int it = 0; it < TOPKK; ++it) {
        float bv = -1.f; int bi = NN;
        for (int j = tid; j < NN; j += 256) {   // ascending scan + strict '>' keeps lowest index on ties
            float q = sc[j];
            if (q > bv) { bv = q; bi = j; }
        }
        rv[tid] = bv; ri[tid] = bi;
        __syncthreads();
        for (int s = 128; s > 0; s >>= 1) {
            if (tid < s) {
                float ov = rv[tid+s]; int oi = ri[tid+s];
                if (ov > rv[tid] || (ov == rv[tid] && oi < ri[tid])) { rv[tid] = ov; ri[tid] = oi; }
            }
            __syncthreads();
        }
        if (tid == 0) {
            adjw[v*13+it] = rv[0];
            adji[v*13+it] = ri[0];
            sc[ri[0]] = -1.f;
        }
        __syncthreads();
    }
    if (tid == 0) {
        float s = 1.f;
        #pragma unroll
        for (int it = 0; it < TOPKK; ++it) s += adjw[v*13+it];
        float inv = 1.f/s;
        #pragma unroll
        for (int it = 0; it < TOPKK; ++it) adjw[v*13+it] *= inv;
        adji[v*13+12] = v;
        adjw[v*13+12] = inv;   // normalized self-loop
    }
}

// ---------------- main: h1 -> hop1 -> hop2 -> MLP(r16), per (b, t-group) block ----------------
// Register-pressure-first design: only racc[SN][16] persists across phases.
// amdgpu_waves_per_eu(3,3): LDS (144 KB) caps the CU at 1 block = 12 waves =
// 3 waves/EU, so pin the allocator's occupancy target there (VGPR cap ~168).
// With an open-ended range (launch_bounds min-only) the allocator targeted
// higher occupancy and spilled ~500 B/thread/iter to scratch -> 850+ MB HBM.
__global__ __attribute__((amdgpu_flat_work_group_size(NTH, NTH), amdgpu_waves_per_eu(3, 3)))
void main_kernel(
    const float* __restrict__ x, float* __restrict__ ws,
    const float* __restrict__ mw, const float* __restrict__ mb,
    const float* __restrict__ rw1, const float* __restrict__ rb1)
{
    const float* ew   = ws + OFF_EW;
    const float* eb   = ws + OFF_EB;
    const float* adjw = ws + OFF_ADJW;
    const int*   adji = (const int*)ws + OFF_ADJI;
    float*       part = ws + OFF_PART;

    // rotated-chunk layouts: chunk k (channels 4k..4k+3) of node n lives at slot n*4 + ((k+n)&3)
    __shared__ float4  sl4[NN*4];   // 96000 B : h1 slice fp32
    __shared__ ushort4 hb4[NN*4];   // 48000 B : hop1 slice bf16

    const int tid = threadIdx.x;
    const int b = blockIdx.x >> 5;
    const int g = blockIdx.x & 31;
    const int t0 = (g*TLEN) >> 5;
    const int t1 = ((g+1)*TLEN) >> 5;

    float racc[SN][16];
    #pragma unroll
    for (int s = 0; s < SN; ++s)
        #pragma unroll
        for (int o = 0; o < 16; ++o) racc[s][o] = 0.f;

    for (int t = t0; t < t1; ++t) {
        // ---- Phase A: effective 7-tap conv -> h1 slice into LDS ----
        #pragma unroll
        for (int s = 0; s < SN; ++s) {
            int v = tid + NTH*s;
            if (v < NN) {
                float xv[7];
                #pragma unroll
                for (int d = 0; d < 7; ++d) xv[d] = x[(b*TIN + t + d)*NN + v];
                #pragma unroll
                for (int k = 0; k < 4; ++k) {
                    float hc[4];
                    #pragma unroll
                    for (int u = 0; u < 4; ++u) {
                        int c = 4*k + u;
                        float a = eb[c];
                        #pragma unroll
                        for (int d = 0; d < 7; ++d) a += ew[c*7+d]*xv[d];
                        hc[u] = a > 0.f ? a : 0.f;
                    }
                    sl4[v*4 + ((k+v)&3)] = make_float4(hc[0],hc[1],hc[2],hc[3]);
                }
            }
        }
        __syncthreads();
        // ---- Phase B: hop1 = 0.2*h1own + 0.8*A@h1 ; store bf16 ----
        #pragma unroll
        for (int s = 0; s < SN; ++s) {
            int v = tid + NTH*s;
            if (v < NN) {
                float hop1[16];
                #pragma unroll
                for (int k = 0; k < 4; ++k) {
                    float4 gv = sl4[v*4 + ((k+v)&3)];
                    hop1[4*k+0] = 0.2f*gv.x;
                    hop1[4*k+1] = 0.2f*gv.y;
                    hop1[4*k+2] = 0.2f*gv.z;
                    hop1[4*k+3] = 0.2f*gv.w;
                }
                int base = v*13;
                #pragma unroll
                for (int j = 0; j < 13; ++j) {
                    int nb = adji[base+j];
                    float wj = 0.8f*adjw[base+j];
                    #pragma unroll
                    for (int k = 0; k < 4; ++k) {
                        float4 gv = sl4[nb*4 + ((k+nb)&3)];
                        hop1[4*k+0] += wj*gv.x;
                        hop1[4*k+1] += wj*gv.y;
                        hop1[4*k+2] += wj*gv.z;
                        hop1[4*k+3] += wj*gv.w;
                    }
                }
                #pragma unroll
                for (int k = 0; k < 4; ++k) {
                    ushort4 u4;
                    u4.x = f2bf(hop1[4*k+0]);
                    u4.y = f2bf(hop1[4*k+1]);
                    u4.z = f2bf(hop1[4*k+2]);
                    u4.w = f2bf(hop1[4*k+3]);
                    hb4[v*4 + ((k+v)&3)] = u4;
                }
            }
        }
        __syncthreads();
        // ---- Phase D: hop2 gather + chunk-wise mw fold + rw1 ; accumulate racc ----
        #pragma unroll
        for (int s = 0; s < SN; ++s) {
            int v = tid + NTH*s;
            if (v < NN) {
                float y16[16];
                #pragma unroll
                for (int o = 0; o < 16; ++o) y16[o] = mb[o];
                float hop2[16];
                // own h1 (fp32): hop2 base + fold mw[:,0:16]
                #pragma unroll
                for (int k = 0; k < 4; ++k) {
                    float4 gv = sl4[v*4 + ((k+v)&3)];
                    float hv[4] = {gv.x, gv.y, gv.z, gv.w};
                    #pragma unroll
                    for (int u = 0; u < 4; ++u) {
                        hop2[4*k+u] = 0.2f*hv[u];
                        #pragma unroll
                        for (int o = 0; o < 16; ++o) y16[o] += mw[o*48 + 4*k+u]*hv[u];
                    }
                }
                // own hop1 (bf16): fold mw[:,16:32]
                #pragma unroll
                for (int k = 0; k < 4; ++k) {
                    ushort4 u4 = hb4[v*4 + ((k+v)&3)];
                    float hv[4] = {bf2f(u4.x), bf2f(u4.y), bf2f(u4.z), bf2f(u4.w)};
                    #pragma unroll
                    for (int u = 0; u < 4; ++u)
                        #pragma unroll
                        for (int o = 0; o < 16; ++o) y16[o] += mw[o*48+16 + 4*k+u]*hv[u];
                }
                // gather hop2
                int base = v*13;
                #pragma unroll
                for (int j = 0; j < 13; ++j) {
                    int nb = adji[base+j];
                    float wj = 0.8f*adjw[base+j];
                    #pragma unroll
                    for (int k = 0; k < 4; ++k) {
                        ushort4 u4 = hb4[nb*4 + ((k+nb)&3)];
                        hop2[4*k+0] += wj*bf2f(u4.x);
                        hop2[4*k+1] += wj*bf2f(u4.y);
                        hop2[4*k+2] += wj*bf2f(u4.z);
                        hop2[4*k+3] += wj*bf2f(u4.w);
                    }
                }
                // fold mw[:,32:48] + relu
                #pragma unroll
                for (int o = 0; o < 16; ++o) {
                    float a = y16[o];
                    #pragma unroll
                    for (int c = 0; c < 16; ++c) a += mw[o*48+32+c]*hop2[c];
                    y16[o] = a > 0.f ? a : 0.f;
                }
                // r16 = relu(rw1@y16 + rb1) ; racc += r16
                #pragma unroll
                for (int o = 0; o < 16; ++o) {
                    float a = rb1[o];
                    #pragma unroll
                    for (int i = 0; i < 16; ++i) a += rw1[o*16+i]*y16[i];
                    racc[s][o] += (a > 0.f ? a : 0.f);
                }
            }
        }
        __syncthreads();   // D reads sl4/hb4; next-t A/B overwrite them
    }
    #pragma unroll
    for (int s = 0; s < SN; ++s) {
        int v = tid + NTH*s;
        if (v < NN) {
            #pragma unroll
            for (int o = 0; o < 16; ++o)
                part[((b*NG + g)*16 + o)*NN + v] = racc[s][o];
        }
    }
}

// ---------------- reduce: sum 32 t-group racc partials, apply rw2/rb2, mean ----------------
__global__ __launch_bounds__(256) void reduce_kernel(const float* __restrict__ ws,
                                                     const float* __restrict__ rw2,
                                                     const float* __restrict__ rb2,
                                                     float* __restrict__ out)
{
    const float* part = ws + OFF_PART;
    int idx = blockIdx.x*256 + threadIdx.x;   // idx over b*NN + v
    if (idx >= BB*NN) return;
    int v = idx % NN;
    int b = idx / NN;
    float s16[16];
    #pragma unroll
    for (int c = 0; c < 16; ++c) s16[c] = 0.f;
    for (int g = 0; g < NG; ++g) {
        #pragma unroll
        for (int c = 0; c < 16; ++c)
            s16[c] += part[((b*NG + g)*16 + c)*NN + v];
    }
    #pragma unroll
    for (int c = 0; c < 16; ++c) s16[c] *= (1.0f/TLEN);
    #pragma unroll
    for (int o = 0; o < TOUTC; ++o) {
        float a = rb2[o];
        #pragma unroll
        for (int c = 0; c < 16; ++c) a += rw2[o*16+c]*s16[c];
        out[(b*TOUTC + o)*NN + v] = a;
    }
}

extern "C" void kernel_launch(void* const* d_in, const int* in_sizes, int n_in,
                              void* d_out, int out_size, void* d_ws, size_t ws_size,
                              hipStream_t stream)
{
    const float* x   = (const float*)d_in[0];
    const float* pw  = (const float*)d_in[1];
    const float* pb  = (const float*)d_in[2];
    const float* tw2 = (const float*)d_in[3];
    const float* tb2 = (const float*)d_in[4];
    const float* tw3 = (const float*)d_in[5];
    const float* tb3 = (const float*)d_in[6];
    const float* tw6 = (const float*)d_in[7];
    const float* tb6 = (const float*)d_in[8];
    const float* tw7 = (const float*)d_in[9];
    const float* tb7 = (const float*)d_in[10];
    const float* e1  = (const float*)d_in[11];
    const float* e2  = (const float*)d_in[12];
    const float* gw1 = (const float*)d_in[13];
    const float* gb1 = (const float*)d_in[14];
    const float* gw2 = (const float*)d_in[15];
    const float* gb2 = (const float*)d_in[16];
    const float* mw  = (const float*)d_in[17];
    const float* mb  = (const float*)d_in[18];
    const float* rw1 = (const float*)d_in[19];
    const float* rb1 = (const float*)d_in[20];
    const float* rw2 = (const float*)d_in[21];
    const float* rb2 = (const float*)d_in[22];
    float* ws  = (float*)d_ws;
    float* out = (float*)d_out;

    prep_kernel<<<(NN + 255)/256, 256, 0, stream>>>(e1,e2,gw1,gb1,gw2,gb2,pw,pb,
                                                    tw2,tb2,tw3,tb3,tw6,tb6,tw7,tb7, ws);
    graph_kernel<<<NN, 256, 0, stream>>>(ws);
    main_kernel<<<BB*NG, NTH, 0, stream>>>(x, ws, mw, mb, rw1, rb1);
    reduce_kernel<<<(BB*NN + 255)/256, 256, 0, stream>>>(ws, rw2, rb2, out);
}